// Round 2
// baseline (990.004 us; speedup 1.0000x reference)
//
#include <hip/hip_runtime.h>

#define DIM 64

// ---------------- fallback (round-1) atomic kernel ----------------
__global__ void coo_scatter_kernel(const float* __restrict__ user_emb,
                                   const float* __restrict__ entity_emb,
                                   const int* __restrict__ rows,
                                   const int* __restrict__ cols,
                                   const float* __restrict__ vals,
                                   float* __restrict__ entity_agg,
                                   float* __restrict__ user_agg,
                                   int nnz) {
    long long tid = (long long)blockIdx.x * blockDim.x + threadIdx.x;
    long long total = (long long)nnz * DIM;
    if (tid >= total) return;
    int edge = (int)(tid >> 6);
    int d = (int)(tid & 63);
    int r = rows[edge];
    int c = cols[edge];
    float v = vals[edge];
    atomicAdd(&entity_agg[c * DIM + d], v * user_emb[r * DIM + d]);
    atomicAdd(&user_agg[r * DIM + d], v * entity_emb[c * DIM + d]);
}

// ---------------- bucketed gather path ----------------

// Pass 1: histogram of edges per output row (entity bins [0,ne), user bins [ne,nb))
__global__ void count_kernel(const int* __restrict__ rows,
                             const int* __restrict__ cols,
                             int* __restrict__ cnt, int ne, int nnz) {
    int i = blockIdx.x * blockDim.x + threadIdx.x;
    if (i >= nnz) return;
    atomicAdd(&cnt[cols[i]], 1);
    atomicAdd(&cnt[ne + rows[i]], 1);
}

// Pass 2: exclusive scan over nb counters (single block, 1024 threads)
__global__ void scan_kernel(const int* __restrict__ cnt,
                            int* __restrict__ offs,
                            int* __restrict__ cursor, int nb) {
    __shared__ int partial[1024];
    int t = threadIdx.x;
    int chunk = (nb + 1023) / 1024;
    int s = t * chunk;
    int e = s + chunk; if (e > nb) e = nb;
    int sum = 0;
    for (int i = s; i < e; ++i) sum += cnt[i];
    partial[t] = sum;
    __syncthreads();
    if (t == 0) {
        int run = 0;
        for (int i = 0; i < 1024; ++i) { int v = partial[i]; partial[i] = run; run += v; }
        offs[nb] = run;  // == 2*nnz
    }
    __syncthreads();
    int off = partial[t];
    for (int i = s; i < e; ++i) {
        offs[i] = off;
        cursor[i] = off;
        off += cnt[i];
    }
}

// Pass 3: scatter edge payloads {src_index, val} into bucket slots
__global__ void fill_kernel(const int* __restrict__ rows,
                            const int* __restrict__ cols,
                            const float* __restrict__ vals,
                            int* __restrict__ cursor,
                            uint2* __restrict__ payload, int ne, int nnz) {
    int i = blockIdx.x * blockDim.x + threadIdx.x;
    if (i >= nnz) return;
    int r = rows[i], c = cols[i];
    unsigned vb = __float_as_uint(vals[i]);
    int s1 = atomicAdd(&cursor[c], 1);          // entity bucket gets user index
    payload[s1] = make_uint2((unsigned)r, vb);
    int s2 = atomicAdd(&cursor[ne + r], 1);     // user bucket gets entity index
    payload[s2] = make_uint2((unsigned)c, vb);
}

// Pass 4: one wave per output row; gather + reduce, single non-atomic write.
__global__ void agg_kernel(const float* __restrict__ user_emb,
                           const float* __restrict__ entity_emb,
                           const int* __restrict__ offs,
                           const uint2* __restrict__ payload,
                           float* __restrict__ out, int ne, int nb) {
    int wave = blockIdx.x * (blockDim.x >> 6) + (threadIdx.x >> 6);
    int lane = threadIdx.x & 63;
    if (wave >= nb) return;
    const float* __restrict__ src = (wave < ne) ? user_emb : entity_emb;
    int beg = offs[wave];
    int end = offs[wave + 1];
    float acc0 = 0.f, acc1 = 0.f, acc2 = 0.f, acc3 = 0.f;
    int i = beg;
    for (; i + 3 < end; i += 4) {
        uint2 p0 = payload[i + 0];
        uint2 p1 = payload[i + 1];
        uint2 p2 = payload[i + 2];
        uint2 p3 = payload[i + 3];
        float e0 = src[(size_t)p0.x * DIM + lane];
        float e1 = src[(size_t)p1.x * DIM + lane];
        float e2 = src[(size_t)p2.x * DIM + lane];
        float e3 = src[(size_t)p3.x * DIM + lane];
        acc0 += __uint_as_float(p0.y) * e0;
        acc1 += __uint_as_float(p1.y) * e1;
        acc2 += __uint_as_float(p2.y) * e2;
        acc3 += __uint_as_float(p3.y) * e3;
    }
    for (; i < end; ++i) {
        uint2 p = payload[i];
        acc0 += __uint_as_float(p.y) * src[(size_t)p.x * DIM + lane];
    }
    out[(size_t)wave * DIM + lane] = (acc0 + acc1) + (acc2 + acc3);
}

extern "C" void kernel_launch(void* const* d_in, const int* in_sizes, int n_in,
                              void* d_out, int out_size, void* d_ws, size_t ws_size,
                              hipStream_t stream) {
    const float* user_emb   = (const float*)d_in[0];  // [n_users, 64]
    const float* entity_emb = (const float*)d_in[1];  // [n_entities, 64]
    const int*   rows       = (const int*)d_in[2];
    const int*   cols       = (const int*)d_in[3];
    const float* vals       = (const float*)d_in[4];
    int nnz = in_sizes[2];
    int nu  = in_sizes[0] / DIM;   // 100000
    int ne  = in_sizes[1] / DIM;   // 50000
    int nb  = ne + nu;             // 150000 output rows (entity_agg then user_agg)

    float* out = (float*)d_out;    // entity_agg [ne*64] then user_agg [nu*64]

    // workspace layout (ints): cnt[nb] | cursor[nb] | offs[nb+1] | pad | payload[2*nnz] uint2
    size_t n_ints = (size_t)nb * 2 + (size_t)nb + 1;
    size_t pay_off_ints = (n_ints + 1) & ~(size_t)1;  // 8B align
    size_t need = pay_off_ints * 4 + (size_t)2 * nnz * 8;

    if (ws_size < need) {
        // fallback: pure atomic scatter
        float* entity_agg = out;
        float* user_agg   = out + (size_t)ne * DIM;
        hipMemsetAsync(d_out, 0, (size_t)out_size * sizeof(float), stream);
        long long total = (long long)nnz * DIM;
        int block = 256;
        long long grid = (total + block - 1) / block;
        coo_scatter_kernel<<<(int)grid, block, 0, stream>>>(
            user_emb, entity_emb, rows, cols, vals, entity_agg, user_agg, nnz);
        return;
    }

    int*   cnt     = (int*)d_ws;
    int*   cursor  = cnt + nb;
    int*   offs    = cursor + nb;             // nb+1 entries
    uint2* payload = (uint2*)((int*)d_ws + pay_off_ints);

    hipMemsetAsync(cnt, 0, (size_t)nb * sizeof(int), stream);

    int block = 256;
    int gEdges = (nnz + block - 1) / block;
    count_kernel<<<gEdges, block, 0, stream>>>(rows, cols, cnt, ne, nnz);
    scan_kernel<<<1, 1024, 0, stream>>>(cnt, offs, cursor, nb);
    fill_kernel<<<gEdges, block, 0, stream>>>(rows, cols, vals, cursor, payload, ne, nnz);

    int wavesPerBlock = block / 64;  // 4
    int gAgg = (nb + wavesPerBlock - 1) / wavesPerBlock;
    agg_kernel<<<gAgg, block, 0, stream>>>(user_emb, entity_emb, offs, payload, out, ne, nb);
}